// Round 3
// baseline (6181.565 us; speedup 1.0000x reference)
//
#include <hip/hip_runtime.h>
#include <math.h>

#define NN   100000
#define EE   1600000
#define INF_ 64
#define HF   128
#define OUTF 3

#define TE    64      // edges per workgroup
#define TN    64      // nodes per workgroup
#define LDA_E 132     // LDS row stride (floats), edge kernel
#define LDA_C 196     // LDS row stride (floats), node kernel

__device__ __forceinline__ void atomic_fadd(float* p, float v) {
#if defined(__AMDGCN__)
    unsafeAtomicAdd(p, v);   // HW global_atomic_add_f32 (device scope)
#else
    atomicAdd(p, v);
#endif
}

// One dense layer: acc[4 rows][8 cols] over K, activations from LDS,
// weights streamed from global (row-major [K][128], L1/L2 resident).
template<int K, int LDAx, bool RELU>
__device__ __forceinline__ void mlp_layer(float (&acc)[4][8],
    const float (*A)[LDAx], int r0, int cbase,
    const float* __restrict__ W, const float* __restrict__ b)
{
    float4 bb0 = *reinterpret_cast<const float4*>(b + cbase);
    float4 bb1 = *reinterpret_cast<const float4*>(b + cbase + 4);
#pragma unroll
    for (int i = 0; i < 4; ++i) {
        acc[i][0] = bb0.x; acc[i][1] = bb0.y; acc[i][2] = bb0.z; acc[i][3] = bb0.w;
        acc[i][4] = bb1.x; acc[i][5] = bb1.y; acc[i][6] = bb1.z; acc[i][7] = bb1.w;
    }
#pragma unroll 4
    for (int k = 0; k < K; ++k) {
        float a0 = A[r0 + 0][k];
        float a1 = A[r0 + 1][k];
        float a2 = A[r0 + 2][k];
        float a3 = A[r0 + 3][k];
        const float* wr = W + k * HF + cbase;
        float4 w0 = *reinterpret_cast<const float4*>(wr);
        float4 w1 = *reinterpret_cast<const float4*>(wr + 4);
        float w[8] = {w0.x, w0.y, w0.z, w0.w, w1.x, w1.y, w1.z, w1.w};
#pragma unroll
        for (int j = 0; j < 8; ++j) {
            acc[0][j] = fmaf(a0, w[j], acc[0][j]);
            acc[1][j] = fmaf(a1, w[j], acc[1][j]);
            acc[2][j] = fmaf(a2, w[j], acc[2][j]);
            acc[3][j] = fmaf(a3, w[j], acc[3][j]);
        }
    }
    if (RELU) {
#pragma unroll
        for (int i = 0; i < 4; ++i)
#pragma unroll
            for (int j = 0; j < 8; ++j)
                acc[i][j] = fmaxf(acc[i][j], 0.0f);
    }
}

template<int LDAx>
__device__ __forceinline__ void store_acc(float (*A)[LDAx],
    const float (&acc)[4][8], int r0, int cbase)
{
#pragma unroll
    for (int i = 0; i < 4; ++i) {
        *reinterpret_cast<float4*>(&A[r0 + i][cbase]) =
            make_float4(acc[i][0], acc[i][1], acc[i][2], acc[i][3]);
        *reinterpret_cast<float4*>(&A[r0 + i][cbase + 4]) =
            make_float4(acc[i][4], acc[i][5], acc[i][6], acc[i][7]);
    }
}

// ---------------- Edge kernel: message MLP + atomic segment-sum ----------------
__global__ __launch_bounds__(256, 4) void edge_kernel(
    const float* __restrict__ x, const int* __restrict__ ei,
    const float* __restrict__ W0, const float* __restrict__ b0,
    const float* __restrict__ W1, const float* __restrict__ b1,
    const float* __restrict__ W2, const float* __restrict__ b2,
    float* __restrict__ agg)
{
    __shared__ float A[TE][LDA_E];
    __shared__ int ridx[TE];
    const int tid = threadIdx.x;
    const int e0  = blockIdx.x * TE;

    // stage x[row] (64 floats/edge); 4 threads per edge
    {
        const int e = tid >> 2, q = tid & 3;
        const int ge = e0 + e;
        const int r  = ei[ge];
        if (q == 0) ridx[e] = r;
        const float4* xr = reinterpret_cast<const float4*>(x + (size_t)r * INF_);
        float4* Ar = reinterpret_cast<float4*>(&A[e][q * 16]);
#pragma unroll
        for (int u = 0; u < 4; ++u) Ar[u] = xr[q * 4 + u];
    }
    __syncthreads();

    // rel / dist / unit -> cols 64..70
    if (tid < TE) {
        const int ge = e0 + tid;
        const int c  = ei[EE + ge];
        const float* xc = x + (size_t)c * INF_;
        float r0 = xc[0] - A[tid][0];
        float r1 = xc[1] - A[tid][1];
        float r2 = xc[2] - A[tid][2];
        float d  = sqrtf(fmaf(r0, r0, fmaf(r1, r1, r2 * r2))) + 1e-12f;
        float iv = 1.0f / d;
        A[tid][64] = r0; A[tid][65] = r1; A[tid][66] = r2; A[tid][67] = d;
        A[tid][68] = r0 * iv; A[tid][69] = r1 * iv; A[tid][70] = r2 * iv;
    }
    __syncthreads();

    const int et = tid >> 4, ct = tid & 15;
    const int r0 = et * 4, cbase = ct * 8;
    float acc[4][8];

    mlp_layer<71, LDA_E, true>(acc, A, r0, cbase, W0, b0);
    __syncthreads();
    store_acc<LDA_E>(A, acc, r0, cbase);
    __syncthreads();
    mlp_layer<HF, LDA_E, true>(acc, A, r0, cbase, W1, b1);
    __syncthreads();
    store_acc<LDA_E>(A, acc, r0, cbase);
    __syncthreads();
    mlp_layer<HF, LDA_E, true>(acc, A, r0, cbase, W2, b2);

#pragma unroll
    for (int i = 0; i < 4; ++i) {
        const int r = ridx[r0 + i];
        float* ag = agg + (size_t)r * HF + cbase;
#pragma unroll
        for (int j = 0; j < 8; ++j) atomic_fadd(ag + j, acc[i][j]);
    }
}

// ---------------- Node kernel: corrector MLP ----------------
__global__ __launch_bounds__(256, 4) void node_kernel(
    const float* __restrict__ x, const float* __restrict__ agg,
    const float* __restrict__ W0, const float* __restrict__ b0,
    const float* __restrict__ W1, const float* __restrict__ b1,
    const float* __restrict__ W2, const float* __restrict__ b2,
    const float* __restrict__ W3, const float* __restrict__ b3,
    float* __restrict__ out)
{
    __shared__ float A[TN][LDA_C];
    const int tid = threadIdx.x;
    const int n0  = blockIdx.x * TN;

    // stage concat(x[n], agg[n]) -> 192 floats; 4 threads per node
    {
        const int n = tid >> 2, q = tid & 3;
        const int gn = n0 + n;
        if (gn < NN) {
            const float4* xr = reinterpret_cast<const float4*>(x + (size_t)gn * INF_ + q * 16);
            float4* Ax = reinterpret_cast<float4*>(&A[n][q * 16]);
#pragma unroll
            for (int u = 0; u < 4; ++u) Ax[u] = xr[u];
            const float4* ar = reinterpret_cast<const float4*>(agg + (size_t)gn * HF + q * 32);
            float4* Aa = reinterpret_cast<float4*>(&A[n][INF_ + q * 32]);
#pragma unroll
            for (int u = 0; u < 8; ++u) Aa[u] = ar[u];
        }
    }
    __syncthreads();

    const int et = tid >> 4, ct = tid & 15;
    const int r0 = et * 4, cbase = ct * 8;
    float acc[4][8];

    mlp_layer<192, LDA_C, true>(acc, A, r0, cbase, W0, b0);
    __syncthreads();
    store_acc<LDA_C>(A, acc, r0, cbase);
    __syncthreads();
    mlp_layer<HF, LDA_C, true>(acc, A, r0, cbase, W1, b1);
    __syncthreads();
    store_acc<LDA_C>(A, acc, r0, cbase);
    __syncthreads();
    mlp_layer<HF, LDA_C, true>(acc, A, r0, cbase, W2, b2);
    __syncthreads();
    store_acc<LDA_C>(A, acc, r0, cbase);
    __syncthreads();

    // final 128 -> 3
    if (tid < TN * 3) {
        const int n = tid / 3, o = tid - n * 3;
        const int gn = n0 + n;
        if (gn < NN) {
            float s = b3[o];
            for (int k = 0; k < HF; k += 4) {
                float4 av = *reinterpret_cast<const float4*>(&A[n][k]);
                s = fmaf(av.x, W3[(k + 0) * 3 + o], s);
                s = fmaf(av.y, W3[(k + 1) * 3 + o], s);
                s = fmaf(av.z, W3[(k + 2) * 3 + o], s);
                s = fmaf(av.w, W3[(k + 3) * 3 + o], s);
            }
            out[(size_t)gn * 3 + o] = s;
        }
    }
}

extern "C" void kernel_launch(void* const* d_in, const int* in_sizes, int n_in,
                              void* d_out, int out_size, void* d_ws, size_t ws_size,
                              hipStream_t stream)
{
    const float* x   = (const float*)d_in[0];
    const int*   ei  = (const int*)  d_in[1];
    const float* mW0 = (const float*)d_in[2];
    const float* mb0 = (const float*)d_in[3];
    const float* mW1 = (const float*)d_in[4];
    const float* mb1 = (const float*)d_in[5];
    const float* mW2 = (const float*)d_in[6];
    const float* mb2 = (const float*)d_in[7];
    const float* cW0 = (const float*)d_in[8];
    const float* cb0 = (const float*)d_in[9];
    const float* cW1 = (const float*)d_in[10];
    const float* cb1 = (const float*)d_in[11];
    const float* cW2 = (const float*)d_in[12];
    const float* cb2 = (const float*)d_in[13];
    const float* cW3 = (const float*)d_in[14];
    const float* cb3 = (const float*)d_in[15];
    float* agg = (float*)d_ws;
    float* out = (float*)d_out;

    hipMemsetAsync(agg, 0, (size_t)NN * HF * sizeof(float), stream);
    edge_kernel<<<EE / TE, 256, 0, stream>>>(x, ei, mW0, mb0, mW1, mb1, mW2, mb2, agg);
    node_kernel<<<(NN + TN - 1) / TN, 256, 0, stream>>>(x, agg, cW0, cb0, cW1, cb1,
                                                        cW2, cb2, cW3, cb3, out);
}

// Round 4
// 2516.012 us; speedup vs baseline: 2.4569x; 2.4569x over previous
//
#include <hip/hip_runtime.h>
#include <math.h>

#define NN   100000
#define EE   1600000
#define INF_ 64
#define HF   128
#define OUTF 3

#define TE    64      // edges per workgroup
#define TN    64      // nodes per workgroup
#define LDA_E 132     // LDS row stride (floats), edge kernel
#define LDA_C 196     // LDS row stride (floats), node kernel

__device__ __forceinline__ void atomic_fadd(float* p, float v) {
#if defined(__AMDGCN__)
    unsafeAtomicAdd(p, v);   // HW global_atomic_add_f32 (device scope)
#else
    atomicAdd(p, v);
#endif
}

// One dense layer: acc[4 rows][8 cols] over K, activations from LDS,
// weights streamed from global (row-major [K][128], L1/L2 resident).
template<int K, int LDAx, bool RELU>
__device__ __forceinline__ void mlp_layer(float (&acc)[4][8],
    const float (*A)[LDAx], int r0, int cbase,
    const float* __restrict__ W, const float* __restrict__ b)
{
    float4 bb0 = *reinterpret_cast<const float4*>(b + cbase);
    float4 bb1 = *reinterpret_cast<const float4*>(b + cbase + 4);
#pragma unroll
    for (int i = 0; i < 4; ++i) {
        acc[i][0] = bb0.x; acc[i][1] = bb0.y; acc[i][2] = bb0.z; acc[i][3] = bb0.w;
        acc[i][4] = bb1.x; acc[i][5] = bb1.y; acc[i][6] = bb1.z; acc[i][7] = bb1.w;
    }
#pragma unroll 4
    for (int k = 0; k < K; ++k) {
        float a0 = A[r0 + 0][k];
        float a1 = A[r0 + 1][k];
        float a2 = A[r0 + 2][k];
        float a3 = A[r0 + 3][k];
        const float* wr = W + k * HF + cbase;
        float4 w0 = *reinterpret_cast<const float4*>(wr);
        float4 w1 = *reinterpret_cast<const float4*>(wr + 4);
        float w[8] = {w0.x, w0.y, w0.z, w0.w, w1.x, w1.y, w1.z, w1.w};
#pragma unroll
        for (int j = 0; j < 8; ++j) {
            acc[0][j] = fmaf(a0, w[j], acc[0][j]);
            acc[1][j] = fmaf(a1, w[j], acc[1][j]);
            acc[2][j] = fmaf(a2, w[j], acc[2][j]);
            acc[3][j] = fmaf(a3, w[j], acc[3][j]);
        }
    }
    if (RELU) {
#pragma unroll
        for (int i = 0; i < 4; ++i)
#pragma unroll
            for (int j = 0; j < 8; ++j)
                acc[i][j] = fmaxf(acc[i][j], 0.0f);
    }
}

template<int LDAx>
__device__ __forceinline__ void store_acc(float (*A)[LDAx],
    const float (&acc)[4][8], int r0, int cbase)
{
#pragma unroll
    for (int i = 0; i < 4; ++i) {
        *reinterpret_cast<float4*>(&A[r0 + i][cbase]) =
            make_float4(acc[i][0], acc[i][1], acc[i][2], acc[i][3]);
        *reinterpret_cast<float4*>(&A[r0 + i][cbase + 4]) =
            make_float4(acc[i][4], acc[i][5], acc[i][6], acc[i][7]);
    }
}

// ---------------- Edge kernel: message MLP + atomic segment-sum ----------------
__global__ __launch_bounds__(256, 4) void edge_kernel(
    const float* __restrict__ x, const int* __restrict__ ei,
    const float* __restrict__ W0, const float* __restrict__ b0,
    const float* __restrict__ W1, const float* __restrict__ b1,
    const float* __restrict__ W2, const float* __restrict__ b2,
    float* __restrict__ agg)
{
    __shared__ float A[TE][LDA_E];
    __shared__ int ridx[TE];
    const int tid = threadIdx.x;
    const int e0  = blockIdx.x * TE;

    // stage x[row] (64 floats/edge); 4 threads per edge
    {
        const int e = tid >> 2, q = tid & 3;
        const int ge = e0 + e;
        const int r  = ei[ge];
        if (q == 0) ridx[e] = r;
        const float4* xr = reinterpret_cast<const float4*>(x + (size_t)r * INF_);
        float4* Ar = reinterpret_cast<float4*>(&A[e][q * 16]);
#pragma unroll
        for (int u = 0; u < 4; ++u) Ar[u] = xr[q * 4 + u];
    }
    __syncthreads();

    // rel / dist / unit -> cols 64..70
    if (tid < TE) {
        const int ge = e0 + tid;
        const int c  = ei[EE + ge];
        const float* xc = x + (size_t)c * INF_;
        float r0 = xc[0] - A[tid][0];
        float r1 = xc[1] - A[tid][1];
        float r2 = xc[2] - A[tid][2];
        float d  = sqrtf(fmaf(r0, r0, fmaf(r1, r1, r2 * r2))) + 1e-12f;
        float iv = 1.0f / d;
        A[tid][64] = r0; A[tid][65] = r1; A[tid][66] = r2; A[tid][67] = d;
        A[tid][68] = r0 * iv; A[tid][69] = r1 * iv; A[tid][70] = r2 * iv;
    }
    __syncthreads();

    const int et = tid >> 4, ct = tid & 15;
    const int r0 = et * 4, cbase = ct * 8;
    float acc[4][8];

    mlp_layer<71, LDA_E, true>(acc, A, r0, cbase, W0, b0);
    __syncthreads();
    store_acc<LDA_E>(A, acc, r0, cbase);
    __syncthreads();
    mlp_layer<HF, LDA_E, true>(acc, A, r0, cbase, W1, b1);
    __syncthreads();
    store_acc<LDA_E>(A, acc, r0, cbase);
    __syncthreads();
    mlp_layer<HF, LDA_E, true>(acc, A, r0, cbase, W2, b2);
    __syncthreads();
    store_acc<LDA_E>(A, acc, r0, cbase);   // layer-3 output back to LDS
    __syncthreads();

    // Coalesced atomic scatter: each wave instruction covers 64 CONSECUTIVE
    // floats of one edge row (8 lanes per 32B sector, each sector touched by
    // exactly one instruction) -> no sector write amplification.
#pragma unroll
    for (int i = 0; i < 32; ++i) {
        const int f = (i << 8) + tid;     // 0..8191 over the 64x128 tile
        const int e = f >> 7;             // edge within tile (wave-uniform)
        const int c = f & 127;            // column 0..127 (lane-consecutive)
        atomic_fadd(agg + (size_t)ridx[e] * HF + c, A[e][c]);
    }
}

// ---------------- Node kernel: corrector MLP ----------------
__global__ __launch_bounds__(256, 4) void node_kernel(
    const float* __restrict__ x, const float* __restrict__ agg,
    const float* __restrict__ W0, const float* __restrict__ b0,
    const float* __restrict__ W1, const float* __restrict__ b1,
    const float* __restrict__ W2, const float* __restrict__ b2,
    const float* __restrict__ W3, const float* __restrict__ b3,
    float* __restrict__ out)
{
    __shared__ float A[TN][LDA_C];
    const int tid = threadIdx.x;
    const int n0  = blockIdx.x * TN;

    // stage concat(x[n], agg[n]) -> 192 floats; 4 threads per node
    {
        const int n = tid >> 2, q = tid & 3;
        const int gn = n0 + n;
        if (gn < NN) {
            const float4* xr = reinterpret_cast<const float4*>(x + (size_t)gn * INF_ + q * 16);
            float4* Ax = reinterpret_cast<float4*>(&A[n][q * 16]);
#pragma unroll
            for (int u = 0; u < 4; ++u) Ax[u] = xr[u];
            const float4* ar = reinterpret_cast<const float4*>(agg + (size_t)gn * HF + q * 32);
            float4* Aa = reinterpret_cast<float4*>(&A[n][INF_ + q * 32]);
#pragma unroll
            for (int u = 0; u < 8; ++u) Aa[u] = ar[u];
        }
    }
    __syncthreads();

    const int et = tid >> 4, ct = tid & 15;
    const int r0 = et * 4, cbase = ct * 8;
    float acc[4][8];

    mlp_layer<192, LDA_C, true>(acc, A, r0, cbase, W0, b0);
    __syncthreads();
    store_acc<LDA_C>(A, acc, r0, cbase);
    __syncthreads();
    mlp_layer<HF, LDA_C, true>(acc, A, r0, cbase, W1, b1);
    __syncthreads();
    store_acc<LDA_C>(A, acc, r0, cbase);
    __syncthreads();
    mlp_layer<HF, LDA_C, true>(acc, A, r0, cbase, W2, b2);
    __syncthreads();
    store_acc<LDA_C>(A, acc, r0, cbase);
    __syncthreads();

    // final 128 -> 3
    if (tid < TN * 3) {
        const int n = tid / 3, o = tid - n * 3;
        const int gn = n0 + n;
        if (gn < NN) {
            float s = b3[o];
            for (int k = 0; k < HF; k += 4) {
                float4 av = *reinterpret_cast<const float4*>(&A[n][k]);
                s = fmaf(av.x, W3[(k + 0) * 3 + o], s);
                s = fmaf(av.y, W3[(k + 1) * 3 + o], s);
                s = fmaf(av.z, W3[(k + 2) * 3 + o], s);
                s = fmaf(av.w, W3[(k + 3) * 3 + o], s);
            }
            out[(size_t)gn * 3 + o] = s;
        }
    }
}

extern "C" void kernel_launch(void* const* d_in, const int* in_sizes, int n_in,
                              void* d_out, int out_size, void* d_ws, size_t ws_size,
                              hipStream_t stream)
{
    const float* x   = (const float*)d_in[0];
    const int*   ei  = (const int*)  d_in[1];
    const float* mW0 = (const float*)d_in[2];
    const float* mb0 = (const float*)d_in[3];
    const float* mW1 = (const float*)d_in[4];
    const float* mb1 = (const float*)d_in[5];
    const float* mW2 = (const float*)d_in[6];
    const float* mb2 = (const float*)d_in[7];
    const float* cW0 = (const float*)d_in[8];
    const float* cb0 = (const float*)d_in[9];
    const float* cW1 = (const float*)d_in[10];
    const float* cb1 = (const float*)d_in[11];
    const float* cW2 = (const float*)d_in[12];
    const float* cb2 = (const float*)d_in[13];
    const float* cW3 = (const float*)d_in[14];
    const float* cb3 = (const float*)d_in[15];
    float* agg = (float*)d_ws;
    float* out = (float*)d_out;

    hipMemsetAsync(agg, 0, (size_t)NN * HF * sizeof(float), stream);
    edge_kernel<<<EE / TE, 256, 0, stream>>>(x, ei, mW0, mb0, mW1, mb1, mW2, mb2, agg);
    node_kernel<<<(NN + TN - 1) / TN, 256, 0, stream>>>(x, agg, cW0, cb0, cW1, cb1,
                                                        cW2, cb2, cW3, cb3, out);
}

// Round 5
// 966.451 us; speedup vs baseline: 6.3961x; 2.6034x over previous
//
#include <hip/hip_runtime.h>
#include <math.h>

#define NN   100000
#define EE   1600000
#define INF_ 64
#define HF   128
#define OUTF 3

#define TE    64      // edges per workgroup
#define TN    64      // nodes per workgroup
#define LDA_C 196     // LDS row stride (floats), node kernel

typedef short  short8  __attribute__((ext_vector_type(8)));
typedef float  float4v __attribute__((ext_vector_type(4)));
typedef unsigned short ushort8 __attribute__((ext_vector_type(8)));

// ---- B-fragment pack geometry (prep kernel output) ----
#define KC0 3                     // K-chunks layer0 (K=71 padded to 96)
#define KC1 4                     // K-chunks layers1/2 (K=128)
#define L0_FRAG (8*KC0*64*8)      // 12288 ushorts
#define L1_FRAG (8*KC1*64*8)      // 16384 ushorts
#define OFF_B0H 0
#define OFF_B0L (OFF_B0H + L0_FRAG)
#define OFF_B1H (OFF_B0L + L0_FRAG)
#define OFF_B1L (OFF_B1H + L1_FRAG)
#define OFF_B2H (OFF_B1L + L1_FRAG)
#define OFF_B2L (OFF_B2H + L1_FRAG)
#define FRAG_TOTAL (OFF_B2L + L1_FRAG)   // 90112 ushorts = 180224 B

__device__ __forceinline__ void atomic_fadd(float* p, float v) {
#if defined(__AMDGCN__)
    unsafeAtomicAdd(p, v);
#else
    atomicAdd(p, v);
#endif
}

__device__ __forceinline__ void split2(float v, unsigned short& h, unsigned short& l) {
    unsigned int bits = __float_as_uint(v);
    h = (unsigned short)(bits >> 16);
    float hf = __uint_as_float(bits & 0xffff0000u);
    l = (unsigned short)(__float_as_uint(v - hf) >> 16);
}

// ---------------- prep: pack msg weights into per-lane MFMA B-fragments ----------------
__global__ void prep_kernel(const float* __restrict__ W0, const float* __restrict__ W1,
                            const float* __restrict__ W2, unsigned short* __restrict__ frag)
{
    int t = blockIdx.x * 256 + threadIdx.x;
    int layer, idx;
    if (t < L0_FRAG)                 { layer = 0; idx = t; }
    else if (t < L0_FRAG + L1_FRAG)  { layer = 1; idx = t - L0_FRAG; }
    else if (t < L0_FRAG + 2*L1_FRAG){ layer = 2; idx = t - L0_FRAG - L1_FRAG; }
    else return;
    const int KC    = (layer == 0) ? KC0 : KC1;
    const int Ktrue = (layer == 0) ? 71  : 128;
    const float* W  = (layer == 0) ? W0 : ((layer == 1) ? W1 : W2);
    const int b    = idx & 7;
    const int lane = (idx >> 3) & 63;
    const int kc   = (idx >> 9) % KC;
    const int nt   = (idx >> 9) / KC;
    const int k = kc * 32 + (lane >> 4) * 8 + b;
    const int j = nt * 16 + (lane & 15);
    float v = (k < Ktrue) ? W[k * HF + j] : 0.0f;
    unsigned short h, l;
    split2(v, h, l);
    const int oh = (layer == 0) ? OFF_B0H : ((layer == 1) ? OFF_B1H : OFF_B2H);
    const int ol = oh + ((layer == 0) ? L0_FRAG : L1_FRAG);
    frag[oh + idx] = h;
    frag[ol + idx] = l;
}

// ---------------- edge kernel: MFMA message MLP + coalesced atomic scatter ----------------
template<int KC>
__device__ __forceinline__ void layer_mm(float4v (&acc)[4][2],
    const unsigned short* Ah, const unsigned short* Al,
    const unsigned short* __restrict__ Bh, const unsigned short* __restrict__ Bl,
    int lane, int w)
{
    const int g  = lane >> 4;
    const int lm = lane & 15;
#pragma unroll
    for (int kc = 0; kc < KC; ++kc) {
        short8 bh[2], bl[2], ah[4], al[4];
#pragma unroll
        for (int n = 0; n < 2; ++n) {
            const int nt = 2 * w + n;
            const size_t off = ((size_t)(nt * KC + kc) * 64 + lane) * 8;
            bh[n] = *reinterpret_cast<const short8*>(Bh + off);
            bl[n] = *reinterpret_cast<const short8*>(Bl + off);
        }
#pragma unroll
        for (int m = 0; m < 4; ++m) {
            const int row  = m * 16 + lm;
            const int slot = (kc * 4 + g) ^ (row & 7);
            const int idx  = row * 128 + slot * 8;
            ah[m] = *reinterpret_cast<const short8*>(&Ah[idx]);
            al[m] = *reinterpret_cast<const short8*>(&Al[idx]);
        }
#pragma unroll
        for (int m = 0; m < 4; ++m)
#pragma unroll
            for (int n = 0; n < 2; ++n) {
                acc[m][n] = __builtin_amdgcn_mfma_f32_16x16x32_bf16(ah[m], bh[n], acc[m][n], 0, 0, 0);
                acc[m][n] = __builtin_amdgcn_mfma_f32_16x16x32_bf16(al[m], bh[n], acc[m][n], 0, 0, 0);
                acc[m][n] = __builtin_amdgcn_mfma_f32_16x16x32_bf16(ah[m], bl[n], acc[m][n], 0, 0, 0);
            }
    }
}

__device__ __forceinline__ void write_back(float4v (&acc)[4][2],
    unsigned short* Ah, unsigned short* Al, const float* __restrict__ bias,
    int lane, int w)
{
    const int g = lane >> 4, lm = lane & 15;
    float bv0 = bias[w * 32 + lm];
    float bv1 = bias[w * 32 + 16 + lm];
#pragma unroll
    for (int m = 0; m < 4; ++m)
#pragma unroll
        for (int n = 0; n < 2; ++n) {
            const float bv = (n == 0) ? bv0 : bv1;
#pragma unroll
            for (int r = 0; r < 4; ++r) {
                const int row = m * 16 + g * 4 + r;
                const int col = w * 32 + n * 16 + lm;
                float v = fmaxf(acc[m][n][r] + bv, 0.0f);
                unsigned short h, l;
                split2(v, h, l);
                const int idx = row * 128 + (((col >> 3) ^ (row & 7)) * 8) + (col & 7);
                Ah[idx] = h;
                Al[idx] = l;
            }
        }
}

__global__ __launch_bounds__(256, 3) void edge_kernel(
    const float* __restrict__ x, const int* __restrict__ ei,
    const unsigned short* __restrict__ frag,
    const float* __restrict__ b0, const float* __restrict__ b1, const float* __restrict__ b2,
    float* __restrict__ agg)
{
    __shared__ unsigned short Ah[64 * 128];
    __shared__ unsigned short Al[64 * 128];
    __shared__ int ridx[TE];
    const int tid  = threadIdx.x;
    const int lane = tid & 63;
    const int w    = tid >> 6;
    const int e0   = blockIdx.x * TE;

    // ---- stage x[row] (cols 0..63), split to bf16 hi/lo, swizzled LDS write ----
    {
        const int e = tid >> 2, q = tid & 3;
        const int r = ei[e0 + e];
        if (q == 0) ridx[e] = r;
        const float4* xr = reinterpret_cast<const float4*>(x + (size_t)r * INF_) + q * 4;
        ushort8 h0, h1, l0, l1;
#pragma unroll
        for (int u = 0; u < 4; ++u) {
            float4 f = xr[u];
            unsigned short ha, hb, hc, hd, la, lb, lc, ld;
            split2(f.x, ha, la); split2(f.y, hb, lb);
            split2(f.z, hc, lc); split2(f.w, hd, ld);
            if (u < 2) {
                h0[u*4+0]=ha; h0[u*4+1]=hb; h0[u*4+2]=hc; h0[u*4+3]=hd;
                l0[u*4+0]=la; l0[u*4+1]=lb; l0[u*4+2]=lc; l0[u*4+3]=ld;
            } else {
                h1[(u-2)*4+0]=ha; h1[(u-2)*4+1]=hb; h1[(u-2)*4+2]=hc; h1[(u-2)*4+3]=hd;
                l1[(u-2)*4+0]=la; l1[(u-2)*4+1]=lb; l1[(u-2)*4+2]=lc; l1[(u-2)*4+3]=ld;
            }
        }
        const int sl0 = (2*q)     ^ (e & 7);
        const int sl1 = (2*q + 1) ^ (e & 7);
        *reinterpret_cast<ushort8*>(&Ah[e*128 + sl0*8]) = h0;
        *reinterpret_cast<ushort8*>(&Ah[e*128 + sl1*8]) = h1;
        *reinterpret_cast<ushort8*>(&Al[e*128 + sl0*8]) = l0;
        *reinterpret_cast<ushort8*>(&Al[e*128 + sl1*8]) = l1;
    }

    // ---- edge features: cols 64..70 (+ zero pad to 95) ----
    if (tid < TE) {
        const int e = tid;
        const int r = ei[e0 + e];
        const int c = ei[EE + e0 + e];
        const float* xr = x + (size_t)r * INF_;
        const float* xc = x + (size_t)c * INF_;
        float r0 = xc[0] - xr[0];
        float r1 = xc[1] - xr[1];
        float r2 = xc[2] - xr[2];
        float d  = sqrtf(fmaf(r0, r0, fmaf(r1, r1, r2 * r2))) + 1e-12f;
        float iv = 1.0f / d;
        float f[8] = {r0, r1, r2, d, r0 * iv, r1 * iv, r2 * iv, 0.0f};
        ushort8 hh, ll;
#pragma unroll
        for (int u = 0; u < 8; ++u) { unsigned short a, b; split2(f[u], a, b); hh[u] = a; ll[u] = b; }
        const int s8 = 8 ^ (e & 7);
        *reinterpret_cast<ushort8*>(&Ah[e*128 + s8*8]) = hh;
        *reinterpret_cast<ushort8*>(&Al[e*128 + s8*8]) = ll;
        ushort8 z = (ushort8)0;
#pragma unroll
        for (int sl = 9; sl <= 11; ++sl) {
            const int s = sl ^ (e & 7);
            *reinterpret_cast<ushort8*>(&Ah[e*128 + s*8]) = z;
            *reinterpret_cast<ushort8*>(&Al[e*128 + s*8]) = z;
        }
    }
    __syncthreads();

    float4v acc[4][2];

    // layer 0 (K=96 padded)
#pragma unroll
    for (int m = 0; m < 4; ++m) for (int n = 0; n < 2; ++n) acc[m][n] = (float4v)0.0f;
    layer_mm<KC0>(acc, Ah, Al, frag + OFF_B0H, frag + OFF_B0L, lane, w);
    __syncthreads();
    write_back(acc, Ah, Al, b0, lane, w);
    __syncthreads();

    // layer 1
#pragma unroll
    for (int m = 0; m < 4; ++m) for (int n = 0; n < 2; ++n) acc[m][n] = (float4v)0.0f;
    layer_mm<KC1>(acc, Ah, Al, frag + OFF_B1H, frag + OFF_B1L, lane, w);
    __syncthreads();
    write_back(acc, Ah, Al, b1, lane, w);
    __syncthreads();

    // layer 2
#pragma unroll
    for (int m = 0; m < 4; ++m) for (int n = 0; n < 2; ++n) acc[m][n] = (float4v)0.0f;
    layer_mm<KC1>(acc, Ah, Al, frag + OFF_B2H, frag + OFF_B2L, lane, w);

    // bias + relu + coalesced atomic scatter straight from accumulators:
    // one instruction = 4 rows x 16 consecutive cols (64B/row-segment, no sector amp)
    {
        const int g = lane >> 4, lm = lane & 15;
        float bv0 = b2[w * 32 + lm];
        float bv1 = b2[w * 32 + 16 + lm];
#pragma unroll
        for (int m = 0; m < 4; ++m)
#pragma unroll
            for (int r = 0; r < 4; ++r) {
                const int rl = m * 16 + g * 4 + r;
                float* base = agg + (size_t)ridx[rl] * HF;
                float v0 = fmaxf(acc[m][0][r] + bv0, 0.0f);
                float v1 = fmaxf(acc[m][1][r] + bv1, 0.0f);
                atomic_fadd(base + w * 32 + lm,      v0);
                atomic_fadd(base + w * 32 + 16 + lm, v1);
            }
    }
}

// ---------------- node kernel (unchanged fp32 path) ----------------
template<int K, int LDAx, bool RELU>
__device__ __forceinline__ void mlp_layer(float (&acc)[4][8],
    const float (*A)[LDAx], int r0, int cbase,
    const float* __restrict__ W, const float* __restrict__ b)
{
    float4 bb0 = *reinterpret_cast<const float4*>(b + cbase);
    float4 bb1 = *reinterpret_cast<const float4*>(b + cbase + 4);
#pragma unroll
    for (int i = 0; i < 4; ++i) {
        acc[i][0] = bb0.x; acc[i][1] = bb0.y; acc[i][2] = bb0.z; acc[i][3] = bb0.w;
        acc[i][4] = bb1.x; acc[i][5] = bb1.y; acc[i][6] = bb1.z; acc[i][7] = bb1.w;
    }
#pragma unroll 4
    for (int k = 0; k < K; ++k) {
        float a0 = A[r0 + 0][k];
        float a1 = A[r0 + 1][k];
        float a2 = A[r0 + 2][k];
        float a3 = A[r0 + 3][k];
        const float* wr = W + k * HF + cbase;
        float4 w0 = *reinterpret_cast<const float4*>(wr);
        float4 w1 = *reinterpret_cast<const float4*>(wr + 4);
        float w[8] = {w0.x, w0.y, w0.z, w0.w, w1.x, w1.y, w1.z, w1.w};
#pragma unroll
        for (int j = 0; j < 8; ++j) {
            acc[0][j] = fmaf(a0, w[j], acc[0][j]);
            acc[1][j] = fmaf(a1, w[j], acc[1][j]);
            acc[2][j] = fmaf(a2, w[j], acc[2][j]);
            acc[3][j] = fmaf(a3, w[j], acc[3][j]);
        }
    }
    if (RELU) {
#pragma unroll
        for (int i = 0; i < 4; ++i)
#pragma unroll
            for (int j = 0; j < 8; ++j)
                acc[i][j] = fmaxf(acc[i][j], 0.0f);
    }
}

template<int LDAx>
__device__ __forceinline__ void store_acc(float (*A)[LDAx],
    const float (&acc)[4][8], int r0, int cbase)
{
#pragma unroll
    for (int i = 0; i < 4; ++i) {
        *reinterpret_cast<float4*>(&A[r0 + i][cbase]) =
            make_float4(acc[i][0], acc[i][1], acc[i][2], acc[i][3]);
        *reinterpret_cast<float4*>(&A[r0 + i][cbase + 4]) =
            make_float4(acc[i][4], acc[i][5], acc[i][6], acc[i][7]);
    }
}

__global__ __launch_bounds__(256, 4) void node_kernel(
    const float* __restrict__ x, const float* __restrict__ agg,
    const float* __restrict__ W0, const float* __restrict__ b0,
    const float* __restrict__ W1, const float* __restrict__ b1,
    const float* __restrict__ W2, const float* __restrict__ b2,
    const float* __restrict__ W3, const float* __restrict__ b3,
    float* __restrict__ out)
{
    __shared__ float A[TN][LDA_C];
    const int tid = threadIdx.x;
    const int n0  = blockIdx.x * TN;

    {
        const int n = tid >> 2, q = tid & 3;
        const int gn = n0 + n;
        if (gn < NN) {
            const float4* xr = reinterpret_cast<const float4*>(x + (size_t)gn * INF_ + q * 16);
            float4* Ax = reinterpret_cast<float4*>(&A[n][q * 16]);
#pragma unroll
            for (int u = 0; u < 4; ++u) Ax[u] = xr[u];
            const float4* ar = reinterpret_cast<const float4*>(agg + (size_t)gn * HF + q * 32);
            float4* Aa = reinterpret_cast<float4*>(&A[n][INF_ + q * 32]);
#pragma unroll
            for (int u = 0; u < 8; ++u) Aa[u] = ar[u];
        }
    }
    __syncthreads();

    const int et = tid >> 4, ct = tid & 15;
    const int r0 = et * 4, cbase = ct * 8;
    float acc[4][8];

    mlp_layer<192, LDA_C, true>(acc, A, r0, cbase, W0, b0);
    __syncthreads();
    store_acc<LDA_C>(A, acc, r0, cbase);
    __syncthreads();
    mlp_layer<HF, LDA_C, true>(acc, A, r0, cbase, W1, b1);
    __syncthreads();
    store_acc<LDA_C>(A, acc, r0, cbase);
    __syncthreads();
    mlp_layer<HF, LDA_C, true>(acc, A, r0, cbase, W2, b2);
    __syncthreads();
    store_acc<LDA_C>(A, acc, r0, cbase);
    __syncthreads();

    if (tid < TN * 3) {
        const int n = tid / 3, o = tid - n * 3;
        const int gn = n0 + n;
        if (gn < NN) {
            float s = b3[o];
            for (int k = 0; k < HF; k += 4) {
                float4 av = *reinterpret_cast<const float4*>(&A[n][k]);
                s = fmaf(av.x, W3[(k + 0) * 3 + o], s);
                s = fmaf(av.y, W3[(k + 1) * 3 + o], s);
                s = fmaf(av.z, W3[(k + 2) * 3 + o], s);
                s = fmaf(av.w, W3[(k + 3) * 3 + o], s);
            }
            out[(size_t)gn * 3 + o] = s;
        }
    }
}

extern "C" void kernel_launch(void* const* d_in, const int* in_sizes, int n_in,
                              void* d_out, int out_size, void* d_ws, size_t ws_size,
                              hipStream_t stream)
{
    const float* x   = (const float*)d_in[0];
    const int*   ei  = (const int*)  d_in[1];
    const float* mW0 = (const float*)d_in[2];
    const float* mb0 = (const float*)d_in[3];
    const float* mW1 = (const float*)d_in[4];
    const float* mb1 = (const float*)d_in[5];
    const float* mW2 = (const float*)d_in[6];
    const float* mb2 = (const float*)d_in[7];
    const float* cW0 = (const float*)d_in[8];
    const float* cb0 = (const float*)d_in[9];
    const float* cW1 = (const float*)d_in[10];
    const float* cb1 = (const float*)d_in[11];
    const float* cW2 = (const float*)d_in[12];
    const float* cb2 = (const float*)d_in[13];
    const float* cW3 = (const float*)d_in[14];
    const float* cb3 = (const float*)d_in[15];
    float* agg = (float*)d_ws;
    float* out = (float*)d_out;

    const size_t AGG_BYTES = (size_t)NN * HF * sizeof(float);
    unsigned short* frag;
    if (ws_size >= AGG_BYTES + (size_t)FRAG_TOTAL * 2 + 64)
        frag = (unsigned short*)((char*)d_ws + AGG_BYTES);
    else
        frag = (unsigned short*)d_out;   // 180KB fits in 1.2MB out; node_kernel rewrites out afterwards

    hipMemsetAsync(agg, 0, AGG_BYTES, stream);
    prep_kernel<<<(L0_FRAG + 2 * L1_FRAG) / 256, 256, 0, stream>>>(mW0, mW1, mW2, frag);
    edge_kernel<<<EE / TE, 256, 0, stream>>>(x, ei, frag, mb0, mb1, mb2, agg);
    node_kernel<<<(NN + TN - 1) / TN, 256, 0, stream>>>(x, agg, cW0, cb0, cW1, cb1,
                                                        cW2, cb2, cW3, cb3, out);
}

// Round 12
// 808.472 us; speedup vs baseline: 7.6460x; 1.1954x over previous
//
#include <hip/hip_runtime.h>
#include <math.h>

#define NN   100000
#define EE   1600000
#define INF_ 64
#define HF   128
#define OUTF 3

#define TE    64
#define TN    64
#define LDA_C 196     // fp32 fallback node kernel LDS stride

typedef short  short8  __attribute__((ext_vector_type(8)));
typedef float  float4v __attribute__((ext_vector_type(4)));
typedef unsigned int uint4v __attribute__((ext_vector_type(4)));

// ---- B-fragment pack geometry (ushort counts) ----
#define L_M0  (8*3*64*8)     // msg W0: K=71->96, KC=3, N=128 -> 12288
#define L_M12 (8*4*64*8)     // msg W1/W2: KC=4, N=128 -> 16384
#define L_C0  (8*6*64*8)     // corr W0: K=192, KC=6, N=128 -> 24576
#define L_C12 (8*4*64*8)     // corr W1/W2 -> 16384
#define L_C3  (8*4*64*1)     // corr W3: K=128, N=3->16 -> 2048

#define OFF_M0H 0
#define OFF_M0L (OFF_M0H + L_M0)
#define OFF_M1H (OFF_M0L + L_M0)
#define OFF_M1L (OFF_M1H + L_M12)
#define OFF_M2H (OFF_M1L + L_M12)
#define OFF_M2L (OFF_M2H + L_M12)
#define OFF_C0H (OFF_M2L + L_M12)
#define OFF_C0L (OFF_C0H + L_C0)
#define OFF_C1H (OFF_C0L + L_C0)
#define OFF_C1L (OFF_C1H + L_C12)
#define OFF_C2H (OFF_C1L + L_C12)
#define OFF_C2L (OFF_C2H + L_C12)
#define OFF_C3H (OFF_C2L + L_C12)
#define OFF_C3L (OFF_C3H + L_C3)
#define FRAG_TOTAL (OFF_C3L + L_C3)      // 208896 ushorts = 417792 B
#define PREP_N (FRAG_TOTAL / 2)          // 104448 h-elements

// cumulative H-element boundaries for prep dispatch (BUGFIX vs round 6:
// previous chain compared t against frag-buffer offsets OFF_x L, which
// interleave H+L regions -> negative idx for t in [12288,24576) -> OOB write)
#define CUM_M0 (L_M0)             // 12288
#define CUM_M1 (CUM_M0 + L_M12)   // 28672
#define CUM_M2 (CUM_M1 + L_M12)   // 45056
#define CUM_C0 (CUM_M2 + L_C0)    // 69632
#define CUM_C1 (CUM_C0 + L_C12)   // 86016
#define CUM_C2 (CUM_C1 + L_C12)   // 102400
// CUM_C3 = CUM_C2 + L_C3 = 104448 == PREP_N

__device__ __forceinline__ void atomic_fadd(float* p, float v) {
#if defined(__AMDGCN__)
    unsafeAtomicAdd(p, v);
#else
    atomicAdd(p, v);
#endif
}

__device__ __forceinline__ void split2(float v, unsigned short& h, unsigned short& l) {
    unsigned int bits = __float_as_uint(v);
    h = (unsigned short)(bits >> 16);
    float hf = __uint_as_float(bits & 0xffff0000u);
    l = (unsigned short)(__float_as_uint(v - hf) >> 16);
}

// pack hi-bf16 in high u16, lo-bf16 in low u16
__device__ __forceinline__ unsigned int pack_hl(float v) {
    unsigned int bits = __float_as_uint(v);
    float hf = __uint_as_float(bits & 0xffff0000u);
    unsigned int l = __float_as_uint(v - hf) >> 16;
    return (bits & 0xffff0000u) | l;
}

#define SEL_HI 0x07060302u
#define SEL_LO 0x05040100u
__device__ __forceinline__ short8 unpack8(uint4v a, uint4v b, unsigned int sel) {
    uint4v w;
    w[0] = __builtin_amdgcn_perm(a[1], a[0], sel);
    w[1] = __builtin_amdgcn_perm(a[3], a[2], sel);
    w[2] = __builtin_amdgcn_perm(b[1], b[0], sel);
    w[3] = __builtin_amdgcn_perm(b[3], b[2], sel);
    return *reinterpret_cast<short8*>(&w);
}

// ---------------- prep: pack all weights into per-lane MFMA B-fragments ----------------
__global__ void prep_kernel(const float* __restrict__ mW0, const float* __restrict__ mW1,
                            const float* __restrict__ mW2, const float* __restrict__ cW0,
                            const float* __restrict__ cW1, const float* __restrict__ cW2,
                            const float* __restrict__ cW3, unsigned short* __restrict__ frag)
{
    int t = blockIdx.x * 256 + threadIdx.x;
    if (t >= PREP_N) return;
    const float* W; int KC, Ktrue, Nld, Ntrue, offH, L, idx;
    if      (t < CUM_M0) { W=mW0; KC=3; Ktrue=71;  Nld=128; Ntrue=128; offH=OFF_M0H; L=L_M0;  idx=t; }
    else if (t < CUM_M1) { W=mW1; KC=4; Ktrue=128; Nld=128; Ntrue=128; offH=OFF_M1H; L=L_M12; idx=t-CUM_M0; }
    else if (t < CUM_M2) { W=mW2; KC=4; Ktrue=128; Nld=128; Ntrue=128; offH=OFF_M2H; L=L_M12; idx=t-CUM_M1; }
    else if (t < CUM_C0) { W=cW0; KC=6; Ktrue=192; Nld=128; Ntrue=128; offH=OFF_C0H; L=L_C0;  idx=t-CUM_M2; }
    else if (t < CUM_C1) { W=cW1; KC=4; Ktrue=128; Nld=128; Ntrue=128; offH=OFF_C1H; L=L_C12; idx=t-CUM_C0; }
    else if (t < CUM_C2) { W=cW2; KC=4; Ktrue=128; Nld=128; Ntrue=128; offH=OFF_C2H; L=L_C12; idx=t-CUM_C1; }
    else                 { W=cW3; KC=4; Ktrue=128; Nld=3;   Ntrue=3;   offH=OFF_C3H; L=L_C3;  idx=t-CUM_C2; }
    const int b    = idx & 7;
    const int lane = (idx >> 3) & 63;
    const int kc   = (idx >> 9) % KC;
    const int nt   = (idx >> 9) / KC;
    const int k = kc * 32 + (lane >> 4) * 8 + b;
    const int j = nt * 16 + (lane & 15);
    float v = (k < Ktrue && j < Ntrue) ? W[k * Nld + j] : 0.0f;
    unsigned short h, l;
    split2(v, h, l);
    frag[offH + idx]     = h;
    frag[offH + L + idx] = l;
}

// ---------------- shared MFMA layer machinery (packed-u32 LDS) ----------------
template<int KC, int STRIDE>
__device__ __forceinline__ void layer_mm(float4v (&acc)[4][2],
    const unsigned int* Ahl,
    const unsigned short* __restrict__ Bh, const unsigned short* __restrict__ Bl,
    int lane, int w)
{
    const int g  = lane >> 4;
    const int lm = lane & 15;
#pragma unroll
    for (int kc = 0; kc < KC; ++kc) {
        short8 bh[2], bl[2], ah[4], al[4];
#pragma unroll
        for (int n = 0; n < 2; ++n) {
            const int nt = 2 * w + n;
            const size_t off = ((size_t)(nt * KC + kc) * 64 + lane) * 8;
            bh[n] = *reinterpret_cast<const short8*>(Bh + off);
            bl[n] = *reinterpret_cast<const short8*>(Bl + off);
        }
#pragma unroll
        for (int m = 0; m < 4; ++m) {
            const int row  = m * 16 + lm;
            const int slot = (kc * 4 + g) ^ (row & 7);
            const int idx  = row * STRIDE + slot * 8;
            uint4v a = *reinterpret_cast<const uint4v*>(Ahl + idx);
            uint4v b = *reinterpret_cast<const uint4v*>(Ahl + idx + 4);
            ah[m] = unpack8(a, b, SEL_HI);
            al[m] = unpack8(a, b, SEL_LO);
        }
#pragma unroll
        for (int m = 0; m < 4; ++m)
#pragma unroll
            for (int n = 0; n < 2; ++n) {
                acc[m][n] = __builtin_amdgcn_mfma_f32_16x16x32_bf16(ah[m], bh[n], acc[m][n], 0, 0, 0);
                acc[m][n] = __builtin_amdgcn_mfma_f32_16x16x32_bf16(al[m], bh[n], acc[m][n], 0, 0, 0);
                acc[m][n] = __builtin_amdgcn_mfma_f32_16x16x32_bf16(ah[m], bl[n], acc[m][n], 0, 0, 0);
            }
    }
}

template<int STRIDE>
__device__ __forceinline__ void write_back(float4v (&acc)[4][2],
    unsigned int* Ahl, const float* __restrict__ bias, int lane, int w)
{
    const int g = lane >> 4, lm = lane & 15;
    float bv0 = bias[w * 32 + lm];
    float bv1 = bias[w * 32 + 16 + lm];
#pragma unroll
    for (int m = 0; m < 4; ++m)
#pragma unroll
        for (int n = 0; n < 2; ++n) {
            const float bv = (n == 0) ? bv0 : bv1;
            const int col = w * 32 + n * 16 + lm;
#pragma unroll
            for (int r = 0; r < 4; ++r) {
                const int row = m * 16 + g * 4 + r;
                float v = fmaxf(acc[m][n][r] + bv, 0.0f);
                Ahl[row * STRIDE + (((col >> 3) ^ (row & 7)) * 8) + (col & 7)] = pack_hl(v);
            }
        }
}

// ---------------- edge kernel ----------------
__global__ __launch_bounds__(256, 4) void edge_kernel(
    const float* __restrict__ x, const int* __restrict__ ei,
    const unsigned short* __restrict__ frag,
    const float* __restrict__ b0, const float* __restrict__ b1, const float* __restrict__ b2,
    float* __restrict__ agg)
{
    __shared__ unsigned int Ahl[64 * 128];
    __shared__ int ridx[TE];
    const int tid  = threadIdx.x;
    const int lane = tid & 63;
    const int w    = tid >> 6;
    const int e0   = blockIdx.x * TE;

    // stage x[row] (cols 0..63) packed
    {
        const int e = tid >> 2, q = tid & 3;
        const int r = ei[e0 + e];
        if (q == 0) ridx[e] = r;
        const float4* xr = reinterpret_cast<const float4*>(x + (size_t)r * INF_) + q * 4;
        unsigned int pk[16];
#pragma unroll
        for (int u = 0; u < 4; ++u) {
            float4 f = xr[u];
            pk[u*4+0] = pack_hl(f.x); pk[u*4+1] = pack_hl(f.y);
            pk[u*4+2] = pack_hl(f.z); pk[u*4+3] = pack_hl(f.w);
        }
        const int base = e * 128;
        const int s0 = (2*q)     ^ (e & 7);
        const int s1 = (2*q + 1) ^ (e & 7);
        *reinterpret_cast<uint4v*>(&Ahl[base + s0*8 + 0]) = uint4v{pk[0],  pk[1],  pk[2],  pk[3]};
        *reinterpret_cast<uint4v*>(&Ahl[base + s0*8 + 4]) = uint4v{pk[4],  pk[5],  pk[6],  pk[7]};
        *reinterpret_cast<uint4v*>(&Ahl[base + s1*8 + 0]) = uint4v{pk[8],  pk[9],  pk[10], pk[11]};
        *reinterpret_cast<uint4v*>(&Ahl[base + s1*8 + 4]) = uint4v{pk[12], pk[13], pk[14], pk[15]};
    }

    // edge features cols 64..70 (+ zero pad to 95)
    if (tid < TE) {
        const int e = tid;
        const int r = ei[e0 + e];
        const int c = ei[EE + e0 + e];
        const float* xr = x + (size_t)r * INF_;
        const float* xc = x + (size_t)c * INF_;
        float r0 = xc[0] - xr[0];
        float r1 = xc[1] - xr[1];
        float r2 = xc[2] - xr[2];
        float d  = sqrtf(fmaf(r0, r0, fmaf(r1, r1, r2 * r2))) + 1e-12f;
        float iv = 1.0f / d;
        float f[8] = {r0, r1, r2, d, r0 * iv, r1 * iv, r2 * iv, 0.0f};
        const int base = e * 128;
        const int s8 = 8 ^ (e & 7);
        *reinterpret_cast<uint4v*>(&Ahl[base + s8*8 + 0]) =
            uint4v{pack_hl(f[0]), pack_hl(f[1]), pack_hl(f[2]), pack_hl(f[3])};
        *reinterpret_cast<uint4v*>(&Ahl[base + s8*8 + 4]) =
            uint4v{pack_hl(f[4]), pack_hl(f[5]), pack_hl(f[6]), pack_hl(f[7])};
        uint4v z = {0, 0, 0, 0};
#pragma unroll
        for (int sl = 9; sl <= 11; ++sl) {
            const int s = sl ^ (e & 7);
            *reinterpret_cast<uint4v*>(&Ahl[base + s*8 + 0]) = z;
            *reinterpret_cast<uint4v*>(&Ahl[base + s*8 + 4]) = z;
        }
    }
    __syncthreads();

    float4v acc[4][2];

#pragma unroll
    for (int m = 0; m < 4; ++m) for (int n = 0; n < 2; ++n) acc[m][n] = (float4v)0.0f;
    layer_mm<3, 128>(acc, Ahl, frag + OFF_M0H, frag + OFF_M0L, lane, w);
    __syncthreads();
    write_back<128>(acc, Ahl, b0, lane, w);
    __syncthreads();

#pragma unroll
    for (int m = 0; m < 4; ++m) for (int n = 0; n < 2; ++n) acc[m][n] = (float4v)0.0f;
    layer_mm<4, 128>(acc, Ahl, frag + OFF_M1H, frag + OFF_M1L, lane, w);
    __syncthreads();
    write_back<128>(acc, Ahl, b1, lane, w);
    __syncthreads();

#pragma unroll
    for (int m = 0; m < 4; ++m) for (int n = 0; n < 2; ++n) acc[m][n] = (float4v)0.0f;
    layer_mm<4, 128>(acc, Ahl, frag + OFF_M2H, frag + OFF_M2L, lane, w);

    // bias + relu + coalesced atomic scatter straight from accumulators
    {
        const int g = lane >> 4, lm = lane & 15;
        float bv0 = b2[w * 32 + lm];
        float bv1 = b2[w * 32 + 16 + lm];
#pragma unroll
        for (int m = 0; m < 4; ++m)
#pragma unroll
            for (int r = 0; r < 4; ++r) {
                const int rl = m * 16 + g * 4 + r;
                float* base = agg + (size_t)ridx[rl] * HF;
                float v0 = fmaxf(acc[m][0][r] + bv0, 0.0f);
                float v1 = fmaxf(acc[m][1][r] + bv1, 0.0f);
                atomic_fadd(base + w * 32 + lm,      v0);
                atomic_fadd(base + w * 32 + 16 + lm, v1);
            }
    }
}

// ---------------- node kernel (MFMA) ----------------
__global__ __launch_bounds__(256, 3) void node_mfma(
    const float* __restrict__ x, const float* __restrict__ agg,
    const unsigned short* __restrict__ frag,
    const float* __restrict__ cb0, const float* __restrict__ cb1,
    const float* __restrict__ cb2, const float* __restrict__ cb3,
    float* __restrict__ out)
{
    __shared__ unsigned int Ahl[64 * 192];   // 48 KB
    const int tid  = threadIdx.x;
    const int lane = tid & 63;
    const int w    = tid >> 6;
    const int n0   = blockIdx.x * TN;

    // stage concat(x, agg) packed: 4 threads/node, 6 slots (48 cols) each
    {
        const int e = tid >> 2, q = tid & 3;
        const int gn = n0 + e;
        const int gs = (gn < NN) ? gn : (NN - 1);
        const int base = e * 192;
#pragma unroll
        for (int ss = 0; ss < 6; ++ss) {
            const int s  = q * 6 + ss;
            const int c0 = s * 8;
            const float* src = (c0 < INF_) ? (x + (size_t)gs * INF_ + c0)
                                           : (agg + (size_t)gs * HF + (c0 - INF_));
            float4 f0 = *reinterpret_cast<const float4*>(src);
            float4 f1 = *reinterpret_cast<const float4*>(src + 4);
            const int sw = s ^ (e & 7);
            *reinterpret_cast<uint4v*>(&Ahl[base + sw*8 + 0]) =
                uint4v{pack_hl(f0.x), pack_hl(f0.y), pack_hl(f0.z), pack_hl(f0.w)};
            *reinterpret_cast<uint4v*>(&Ahl[base + sw*8 + 4]) =
                uint4v{pack_hl(f1.x), pack_hl(f1.y), pack_hl(f1.z), pack_hl(f1.w)};
        }
    }
    __syncthreads();

    float4v acc[4][2];

#pragma unroll
    for (int m = 0; m < 4; ++m) for (int n = 0; n < 2; ++n) acc[m][n] = (float4v)0.0f;
    layer_mm<6, 192>(acc, Ahl, frag + OFF_C0H, frag + OFF_C0L, lane, w);
    __syncthreads();
    write_back<192>(acc, Ahl, cb0, lane, w);
    __syncthreads();

#pragma unroll
    for (int m = 0; m < 4; ++m) for (int n = 0; n < 2; ++n) acc[m][n] = (float4v)0.0f;
    layer_mm<4, 192>(acc, Ahl, frag + OFF_C1H, frag + OFF_C1L, lane, w);
    __syncthreads();
    write_back<192>(acc, Ahl, cb1, lane, w);
    __syncthreads();

#pragma unroll
    for (int m = 0; m < 4; ++m) for (int n = 0; n < 2; ++n) acc[m][n] = (float4v)0.0f;
    layer_mm<4, 192>(acc, Ahl, frag + OFF_C2H, frag + OFF_C2L, lane, w);
    __syncthreads();
    write_back<192>(acc, Ahl, cb2, lane, w);
    __syncthreads();

    // tail 128 -> 3 (padded to 16 cols): wave w owns rows w*16..w*16+15
    {
        const int g = lane >> 4, lm = lane & 15;
        float4v acc3 = {0.0f, 0.0f, 0.0f, 0.0f};
#pragma unroll
        for (int kc = 0; kc < 4; ++kc) {
            const size_t off = ((size_t)kc * 64 + lane) * 8;
            short8 bh = *reinterpret_cast<const short8*>(frag + OFF_C3H + off);
            short8 bl = *reinterpret_cast<const short8*>(frag + OFF_C3L + off);
            const int row  = w * 16 + lm;
            const int slot = (kc * 4 + g) ^ (row & 7);
            const int idx  = row * 192 + slot * 8;
            uint4v a = *reinterpret_cast<const uint4v*>(Ahl + idx);
            uint4v b = *reinterpret_cast<const uint4v*>(Ahl + idx + 4);
            short8 ah = unpack8(a, b, SEL_HI);
            short8 al = unpack8(a, b, SEL_LO);
            acc3 = __builtin_amdgcn_mfma_f32_16x16x32_bf16(ah, bh, acc3, 0, 0, 0);
            acc3 = __builtin_amdgcn_mfma_f32_16x16x32_bf16(al, bh, acc3, 0, 0, 0);
            acc3 = __builtin_amdgcn_mfma_f32_16x16x32_bf16(ah, bl, acc3, 0, 0, 0);
        }
        if (lm < OUTF) {
            const float bo = cb3[lm];
#pragma unroll
            for (int r = 0; r < 4; ++r) {
                const int gn = n0 + w * 16 + g * 4 + r;
                if (gn < NN) out[(size_t)gn * OUTF + lm] = acc3[r] + bo;
            }
        }
    }
}

// ---------------- fp32 node kernel (fallback if ws too small for frags) ----------------
template<int K, int LDAx, bool RELU>
__device__ __forceinline__ void mlp_layer(float (&acc)[4][8],
    const float (*A)[LDAx], int r0, int cbase,
    const float* __restrict__ W, const float* __restrict__ b)
{
    float4 bb0 = *reinterpret_cast<const float4*>(b + cbase);
    float4 bb1 = *reinterpret_cast<const float4*>(b + cbase + 4);
#pragma unroll
    for (int i = 0; i < 4; ++i) {
        acc[i][0] = bb0.x; acc[i][1] = bb0.y; acc[i][2] = bb0.z; acc[i][3] = bb0.w;
        acc[i][4] = bb1.x; acc[i][5] = bb1.y; acc[i][6] = bb1.z; acc[i][7] = bb1.w;
    }
#pragma unroll 4
    for (int k = 0; k < K; ++k) {
        float a0 = A[r0 + 0][k], a1 = A[r0 + 1][k], a2 = A[r0 + 2][k], a3 = A[r0 + 3][k];
        const float* wr = W + k * HF + cbase;
        float4 w0 = *reinterpret_cast<const float4*>(wr);
        float4 w1 = *reinterpret_cast<const float4*>(wr + 4);
        float wv[8] = {w0.x, w0.y, w0.z, w0.w, w1.x, w1.y, w1.z, w1.w};
#pragma unroll
        for (int j = 0; j < 8; ++j) {
            acc[0][j] = fmaf(a0, wv[j], acc[0][j]);
            acc[1][j] = fmaf(a1, wv[j], acc[1][j]);
            acc[2][j] = fmaf(a2, wv[j], acc[2][j]);
            acc[3][j] = fmaf(a3, wv[j], acc[3][j]);
        }
    }
    if (RELU) {
#pragma unroll
        for (int i = 0; i < 4; ++i)
#pragma unroll
            for (int j = 0; j < 8; ++j)
                acc[i][j] = fmaxf(acc[i][j], 0.0f);
    }
}

template<int LDAx>
__device__ __forceinline__ void store_acc(float (*A)[LDAx],
    const float (&acc)[4][8], int r0, int cbase)
{
#pragma unroll
    for (int i = 0; i < 4; ++i) {
        *reinterpret_cast<float4*>(&A[r0 + i][cbase]) =
            make_float4(acc[i][0], acc[i][1], acc[i][2], acc[i][3]);
        *reinterpret_cast<float4*>(&A[r0 + i][cbase + 4]) =
            make_float4(acc[i][4], acc[i][5], acc[i][6], acc[i][7]);
    }
}

__global__ __launch_bounds__(256, 4) void node_kernel(
    const float* __restrict__ x, const float* __restrict__ agg,
    const float* __restrict__ W0, const float* __restrict__ b0,
    const float* __restrict__ W1, const float* __restrict__ b1,
    const float* __restrict__ W2, const float* __restrict__ b2,
    const float* __restrict__ W3, const float* __restrict__ b3,
    float* __restrict__ out)
{
    __shared__ float A[TN][LDA_C];
    const int tid = threadIdx.x;
    const int n0  = blockIdx.x * TN;
    {
        const int n = tid >> 2, q = tid & 3;
        const int gn = n0 + n;
        if (gn < NN) {
            const float4* xr = reinterpret_cast<const float4*>(x + (size_t)gn * INF_ + q * 16);
            float4* Ax = reinterpret_cast<float4*>(&A[n][q * 16]);
#pragma unroll
            for (int u = 0; u < 4; ++u) Ax[u] = xr[u];
            const float4* ar = reinterpret_cast<const float4*>(agg + (size_t)gn * HF + q * 32);
            float4* Aa = reinterpret_cast<float4*>(&A[n][INF_ + q * 32]);
#pragma unroll
            for (int u = 0; u < 8; ++u) Aa[u] = ar[u];
        }
    }
    __syncthreads();
    const int et = tid >> 4, ct = tid & 15;
    const int r0 = et * 4, cbase = ct * 8;
    float acc[4][8];
    mlp_layer<192, LDA_C, true>(acc, A, r0, cbase, W0, b0);
    __syncthreads(); store_acc<LDA_C>(A, acc, r0, cbase); __syncthreads();
    mlp_layer<HF, LDA_C, true>(acc, A, r0, cbase, W1, b1);
    __syncthreads(); store_acc<LDA_C>(A, acc, r0, cbase); __syncthreads();
    mlp_layer<HF, LDA_C, true>(acc, A, r0, cbase, W2, b2);
    __syncthreads(); store_acc<LDA_C>(A, acc, r0, cbase); __syncthreads();
    if (tid < TN * 3) {
        const int n = tid / 3, o = tid - n * 3;
        const int gn = n0 + n;
        if (gn < NN) {
            float s = b3[o];
            for (int k = 0; k < HF; k += 4) {
                float4 av = *reinterpret_cast<const float4*>(&A[n][k]);
                s = fmaf(av.x, W3[(k + 0) * 3 + o], s);
                s = fmaf(av.y, W3[(k + 1) * 3 + o], s);
                s = fmaf(av.z, W3[(k + 2) * 3 + o], s);
                s = fmaf(av.w, W3[(k + 3) * 3 + o], s);
            }
            out[(size_t)gn * 3 + o] = s;
        }
    }
}

extern "C" void kernel_launch(void* const* d_in, const int* in_sizes, int n_in,
                              void* d_out, int out_size, void* d_ws, size_t ws_size,
                              hipStream_t stream)
{
    const float* x   = (const float*)d_in[0];
    const int*   ei  = (const int*)  d_in[1];
    const float* mW0 = (const float*)d_in[2];
    const float* mb0 = (const float*)d_in[3];
    const float* mW1 = (const float*)d_in[4];
    const float* mb1 = (const float*)d_in[5];
    const float* mW2 = (const float*)d_in[6];
    const float* mb2 = (const float*)d_in[7];
    const float* cW0 = (const float*)d_in[8];
    const float* cb0 = (const float*)d_in[9];
    const float* cW1 = (const float*)d_in[10];
    const float* cb1 = (const float*)d_in[11];
    const float* cW2 = (const float*)d_in[12];
    const float* cb2 = (const float*)d_in[13];
    const float* cW3 = (const float*)d_in[14];
    const float* cb3 = (const float*)d_in[15];
    float* agg = (float*)d_ws;
    float* out = (float*)d_out;

    const size_t AGG_BYTES  = (size_t)NN * HF * sizeof(float);
    const size_t FRAG_BYTES = (size_t)FRAG_TOTAL * sizeof(unsigned short);
    const bool big_ws = (ws_size >= AGG_BYTES + FRAG_BYTES + 256);
    unsigned short* frag = big_ws ? (unsigned short*)((char*)d_ws + AGG_BYTES)
                                  : (unsigned short*)d_out;   // fallback: frags in out, fp32 node

    hipMemsetAsync(agg, 0, AGG_BYTES, stream);
    prep_kernel<<<(PREP_N + 255) / 256, 256, 0, stream>>>(mW0, mW1, mW2, cW0, cW1, cW2, cW3, frag);
    edge_kernel<<<EE / TE, 256, 0, stream>>>(x, ei, frag, mb0, mb1, mb2, agg);
    if (big_ws)
        node_mfma<<<(NN + TN - 1) / TN, 256, 0, stream>>>(x, agg, frag, cb0, cb1, cb2, cb3, out);
    else
        node_kernel<<<(NN + TN - 1) / TN, 256, 0, stream>>>(x, agg, cW0, cb0, cW1, cb1,
                                                            cW2, cb2, cW3, cb3, out);
}